// Round 10
// baseline (321.832 us; speedup 1.0000x reference)
//
#include <hip/hip_runtime.h>
#include <hip/hip_bf16.h>

// GCN actor-critic, bf16 pipeline:
//   CSR build (counting sort, single-pass fine scatter) ->
//   3x [gather-sum -> MFMA GEMM+ReLU]; layer-3 epilogue emits pi_graph+partials.

#define HID 128
#define NBLK 256       // edge-partition blocks
#define BSH 6          // 64 nodes per coarse bucket
#define SCAN_CHUNK 1024

typedef __attribute__((ext_vector_type(8))) short short8;
typedef __attribute__((ext_vector_type(4))) float f32x4;
typedef __attribute__((ext_vector_type(2))) float f32x2;
typedef __attribute__((ext_vector_type(2))) unsigned int u32x2;

__device__ __forceinline__ unsigned int f2bf(float f) {
    unsigned int u = __float_as_uint(f);
    return (u + 0x7fffu + ((u >> 16) & 1u)) >> 16;   // RNE
}
__device__ __forceinline__ f32x2 bfpair(unsigned int u) {
    u32x2 t = {u << 16, u & 0xffff0000u};
    return __builtin_bit_cast(f32x2, t);
}

// ---------------------------------------------------------------- converts
__global__ __launch_bounds__(256) void f32_to_bf16_kernel(
        const float4* __restrict__ in, ushort4* __restrict__ out, int n4) {
    for (int i = blockIdx.x * blockDim.x + threadIdx.x; i < n4; i += gridDim.x * blockDim.x) {
        float4 v = in[i];
        ushort4 o;
        o.x = (unsigned short)f2bf(v.x); o.y = (unsigned short)f2bf(v.y);
        o.z = (unsigned short)f2bf(v.z); o.w = (unsigned short)f2bf(v.w);
        out[i] = o;
    }
}

// pack all 3 W[128][128] into B-fragment order; also zeros deg[] (n4z int4s).
__global__ __launch_bounds__(256) void pack_w3_kernel(
        const float* __restrict__ W0, const float* __restrict__ W1,
        const float* __restrict__ W2, unsigned short* __restrict__ pw,
        int4* __restrict__ deg4, int n4z) {
    int z = blockIdx.x * blockDim.x + threadIdx.x;
    if (z < n4z) deg4[z] = make_int4(0, 0, 0, 0);
    for (int j = z; j < 3 * 16384; j += gridDim.x * blockDim.x) {
        int jj = j & 16383, which = j >> 14;
        const float* W = (which == 0) ? W0 : (which == 1) ? W1 : W2;
        int i = jj & 7, lane = (jj >> 3) & 63, kk = (jj >> 9) & 3, c = (jj >> 11) & 7;
        int k = kk * 32 + (lane >> 4) * 8 + i;
        int col = c * 16 + (lane & 15);
        pw[j] = (unsigned short)f2bf(W[k * 128 + col]);
    }
}

// ---- 1. coarse histogram (int4 loads) + global per-node degree
__global__ __launch_bounds__(256) void bhist_kernel(const int* __restrict__ dst,
        int* __restrict__ tbl, int* __restrict__ deg, int ne, int nb, int epb) {
    __shared__ int lcnt[1024];
    const int k = blockIdx.x, t = threadIdx.x;
    for (int b = t; b < nb; b += 256) lcnt[b] = 0;
    __syncthreads();
    const int beg = k * epb, end = min(ne, beg + epb);
    int j = beg + t * 4;
    for (; j + 3 < end; j += 1024) {
        int4 d = *(const int4*)(dst + j);
        atomicAdd(&lcnt[d.x >> BSH], 1); atomicAdd(&deg[d.x], 1);
        atomicAdd(&lcnt[d.y >> BSH], 1); atomicAdd(&deg[d.y], 1);
        atomicAdd(&lcnt[d.z >> BSH], 1); atomicAdd(&deg[d.z], 1);
        atomicAdd(&lcnt[d.w >> BSH], 1); atomicAdd(&deg[d.w], 1);
    }
    for (; j < end; ++j) {
        int d = dst[j];
        atomicAdd(&lcnt[d >> BSH], 1); atomicAdd(&deg[d], 1);
    }
    __syncthreads();
    for (int b = t; b < nb; b += 256) tbl[b * NBLK + k] = lcnt[b];
}

// ---- 2. hierarchical exclusive scan of tbl[0..sz)
__global__ __launch_bounds__(256) void scan_p1_kernel(const int* __restrict__ tbl,
        int* __restrict__ bsum, int sz) {
    __shared__ int sh[256];
    const int g = blockIdx.x, t = threadIdx.x;
    const int base = g * SCAN_CHUNK + t * 4;
    int s = 0;
    if (base + 3 < sz) {
        int4 v = *(const int4*)(tbl + base);
        s = v.x + v.y + v.z + v.w;
    } else {
        for (int i = 0; i < 4; ++i) if (base + i < sz) s += tbl[base + i];
    }
    sh[t] = s;
    __syncthreads();
    for (int off = 128; off > 0; off >>= 1) {
        if (t < off) sh[t] += sh[t + off];
        __syncthreads();
    }
    if (t == 0) bsum[g] = sh[0];
}

__global__ __launch_bounds__(256) void scan_p2_kernel(int* __restrict__ bsum, int ng) {
    __shared__ int sh[256];
    const int t = threadIdx.x;
    int v = (t < ng) ? bsum[t] : 0;
    sh[t] = v;
    __syncthreads();
    for (int off = 1; off < 256; off <<= 1) {
        int a = sh[t];
        int b = (t >= off) ? sh[t - off] : 0;
        __syncthreads();
        sh[t] = a + b;
        __syncthreads();
    }
    if (t < ng) bsum[t] = sh[t] - v;   // exclusive
}

__global__ __launch_bounds__(256) void scan_p3_kernel(int* __restrict__ tbl,
        const int* __restrict__ bsum, int sz) {
    __shared__ int sh[256];
    const int g = blockIdx.x, t = threadIdx.x;
    const int base = g * SCAN_CHUNK + t * 4;
    int4 v = make_int4(0, 0, 0, 0);
    if (base + 3 < sz) {
        v = *(const int4*)(tbl + base);
    } else {
        if (base + 0 < sz) v.x = tbl[base + 0];
        if (base + 1 < sz) v.y = tbl[base + 1];
        if (base + 2 < sz) v.z = tbl[base + 2];
    }
    int s = v.x + v.y + v.z + v.w;
    sh[t] = s;
    __syncthreads();
    for (int off = 1; off < 256; off <<= 1) {
        int a = sh[t];
        int b = (t >= off) ? sh[t - off] : 0;
        __syncthreads();
        sh[t] = a + b;
        __syncthreads();
    }
    int pre = bsum[g] + sh[t] - s;
    int o0 = pre, o1 = pre + v.x, o2 = o1 + v.y, o3 = o2 + v.z;
    if (base + 3 < sz) {
        *(int4*)(tbl + base) = make_int4(o0, o1, o2, o3);
    } else {
        if (base + 0 < sz) tbl[base + 0] = o0;
        if (base + 1 < sz) tbl[base + 1] = o1;
        if (base + 2 < sz) tbl[base + 2] = o2;
    }
}

// ---- 3. scatter edges into block-private per-bucket subranges (int4 loads)
__global__ __launch_bounds__(256) void bucket_scatter_kernel(
        const int* __restrict__ src, const int* __restrict__ dst,
        const int* __restrict__ tbl, int* __restrict__ pairs,
        int ne, int nb, int epb) {
    __shared__ int cur[1024];
    const int k = blockIdx.x, t = threadIdx.x;
    for (int b = t; b < nb; b += 256) cur[b] = tbl[b * NBLK + k];
    __syncthreads();
    const int beg = k * epb, end = min(ne, beg + epb);
    int j = beg + t * 4;
    for (; j + 3 < end; j += 1024) {
        int4 d = *(const int4*)(dst + j);
        int4 s = *(const int4*)(src + j);
        int p0 = atomicAdd(&cur[d.x >> BSH], 1); pairs[p0] = (s.x << BSH) | (d.x & 63);
        int p1 = atomicAdd(&cur[d.y >> BSH], 1); pairs[p1] = (s.y << BSH) | (d.y & 63);
        int p2 = atomicAdd(&cur[d.z >> BSH], 1); pairs[p2] = (s.z << BSH) | (d.z & 63);
        int p3 = atomicAdd(&cur[d.w >> BSH], 1); pairs[p3] = (s.w << BSH) | (d.w & 63);
    }
    for (; j < end; ++j) {
        int d = dst[j];
        int pos = atomicAdd(&cur[d >> BSH], 1);
        pairs[pos] = (src[j] << BSH) | (d & 63);
    }
}

// ---- 4. per-bucket fine scatter, single pass (uses deg); writes row_ptr
__global__ __launch_bounds__(256) void fine_scatter_kernel(
        const int* __restrict__ pairs, const int* __restrict__ tbl,
        const int* __restrict__ deg,
        int* __restrict__ row_ptr, int* __restrict__ eidx,
        int ne, int nb, int n) {
    __shared__ int cur[64];
    const int b = blockIdx.x, t = threadIdx.x;
    const int node0 = b << BSH;
    const int beg = tbl[b * NBLK];
    const int end = (b == nb - 1) ? ne : tbl[(b + 1) * NBLK];
    if (t == 0) {
        int run = beg;
        #pragma unroll
        for (int i = 0; i < 64; ++i) { cur[i] = run; run += deg[node0 + i]; }
    }
    __syncthreads();
    if (t < 64 && node0 + t < n) row_ptr[node0 + t] = cur[t];
    if (b == nb - 1 && t == 0) row_ptr[n] = ne;
    __syncthreads();
    for (int j = beg + t; j < end; j += 256) {
        int v = pairs[j];
        int pos = atomicAdd(&cur[v & 63], 1);
        eidx[pos] = v >> BSH;
    }
}

// ------------------------------------------------------------- aggregation
// 32-lane group per node; half = lane>>4 picks even/odd edge, l16 = lane&15
// picks 16B (8 bf16 dims). f32x2 accumulators -> v_pk_add_f32.
#define ACC8(V)  { a01 += bfpair((V).x); a23 += bfpair((V).y);            \
                   a45 += bfpair((V).z); a67 += bfpair((V).w); }

__global__ __launch_bounds__(256) void aggregate_bf_kernel(
        const uint4* __restrict__ xb, const int* __restrict__ row_ptr,
        const int* __restrict__ eidx, uint4* __restrict__ aggb, int n) {
    int g = (int)((blockIdx.x * blockDim.x + threadIdx.x) >> 5);
    int lane = threadIdx.x & 31;
    if (g >= n) return;
    const int half = lane >> 4, l16 = lane & 15;
    const int beg = row_ptr[g], end = row_ptr[g + 1];
    f32x2 a01 = {0.f, 0.f}, a23 = {0.f, 0.f}, a45 = {0.f, 0.f}, a67 = {0.f, 0.f};
    int e = beg;
    for (; e + 16 <= end; e += 16) {
        uint4 v0 = xb[(size_t)eidx[e + 0 + half] * 16 + l16];
        uint4 v1 = xb[(size_t)eidx[e + 2 + half] * 16 + l16];
        uint4 v2 = xb[(size_t)eidx[e + 4 + half] * 16 + l16];
        uint4 v3 = xb[(size_t)eidx[e + 6 + half] * 16 + l16];
        uint4 v4 = xb[(size_t)eidx[e + 8 + half] * 16 + l16];
        uint4 v5 = xb[(size_t)eidx[e + 10 + half] * 16 + l16];
        uint4 v6 = xb[(size_t)eidx[e + 12 + half] * 16 + l16];
        uint4 v7 = xb[(size_t)eidx[e + 14 + half] * 16 + l16];
        ACC8(v0); ACC8(v1); ACC8(v2); ACC8(v3);
        ACC8(v4); ACC8(v5); ACC8(v6); ACC8(v7);
    }
    for (; e + 4 <= end; e += 4) {
        uint4 v0 = xb[(size_t)eidx[e + 0 + half] * 16 + l16];
        uint4 v1 = xb[(size_t)eidx[e + 2 + half] * 16 + l16];
        ACC8(v0); ACC8(v1);
    }
    for (; e < end; e += 2) {
        int idx = e + half;
        uint4 v = make_uint4(0, 0, 0, 0);
        if (idx < end) v = xb[(size_t)eidx[idx] * 16 + l16];
        ACC8(v);
    }
    float acc[8] = {a01.x, a01.y, a23.x, a23.y, a45.x, a45.y, a67.x, a67.y};
    #pragma unroll
    for (int j = 0; j < 8; ++j) acc[j] += __shfl_xor(acc[j], 16);
    if (half == 0) {
        uint4 o;
        o.x = f2bf(acc[0]) | (f2bf(acc[1]) << 16);
        o.y = f2bf(acc[2]) | (f2bf(acc[3]) << 16);
        o.z = f2bf(acc[4]) | (f2bf(acc[5]) << 16);
        o.w = f2bf(acc[6]) | (f2bf(acc[7]) << 16);
        aggb[(size_t)g * 16 + l16] = o;
    }
}

// ---------------------------------------------------------- GEMM bf16 MFMA
__global__ __launch_bounds__(256) void gemm_mfma_kernel(
        const short* __restrict__ A, const short* __restrict__ packw,
        const float* __restrict__ bias, unsigned short* __restrict__ out, int M,
        float* __restrict__ part, float* __restrict__ pig_out,
        const float* __restrict__ w_pg, const float* __restrict__ b_pg) {
    __shared__ float colp[4][128];
    const int w = threadIdx.x >> 6, l = threadIdx.x & 63;
    const int m = l & 15, hi = l >> 4;
    const int row0 = blockIdx.x * 64 + w * 16;
    const int arow = row0 + m;
    const bool valid = arow < M;

    short8 afrag[4];
    #pragma unroll
    for (int kk = 0; kk < 4; ++kk) {
        if (valid)
            afrag[kk] = *(const short8*)(A + (size_t)arow * 128 + kk * 32 + hi * 8);
        else
            afrag[kk] = short8{0, 0, 0, 0, 0, 0, 0, 0};
    }

    f32x4 acc[8] = {};
    #pragma unroll
    for (int kk = 0; kk < 4; ++kk) {
        #pragma unroll
        for (int c = 0; c < 8; ++c) {
            short8 bfrag = *(const short8*)(packw + ((size_t)(c * 4 + kk) * 64 + l) * 8);
            acc[c] = __builtin_amdgcn_mfma_f32_16x16x32_bf16(afrag[kk], bfrag, acc[c], 0, 0, 0);
        }
    }

    float hvv[8][4];
    #pragma unroll
    for (int c = 0; c < 8; ++c) {
        float bcol = bias[c * 16 + m];
        #pragma unroll
        for (int r = 0; r < 4; ++r) {
            int row = row0 + hi * 4 + r;
            float hv = (row < M) ? fmaxf(acc[c][r] + bcol, 0.f) : 0.f;
            hvv[c][r] = hv;
            if (row < M)
                out[(size_t)row * 128 + c * 16 + m] = (unsigned short)f2bf(hv);
        }
    }

    if (w_pg) {
        #pragma unroll
        for (int r = 0; r < 4; ++r) {
            float p = 0.f;
            #pragma unroll
            for (int c = 0; c < 8; ++c) p += hvv[c][r] * w_pg[c * 16 + m];
            #pragma unroll
            for (int off = 1; off < 16; off <<= 1) p += __shfl_xor(p, off);
            int row = row0 + hi * 4 + r;
            if (m == 0 && row < M) pig_out[row] = p + b_pg[0];
        }
        #pragma unroll
        for (int c = 0; c < 8; ++c) {
            float v = hvv[c][0] + hvv[c][1] + hvv[c][2] + hvv[c][3];
            v += __shfl_xor(v, 16);
            v += __shfl_xor(v, 32);
            if (hi == 0) colp[w][c * 16 + m] = v;
        }
        __syncthreads();
        const int t = threadIdx.x;
        if (t < 128)
            part[(size_t)blockIdx.x * 128 + t] =
                colp[0][t] + colp[1][t] + colp[2][t] + colp[3][t];
    }
}

// ---------------------------------------------------------------- head
__global__ __launch_bounds__(1024) void head_final_kernel(
        const float* __restrict__ part, int nparts,
        const float* __restrict__ w_v, const float* __restrict__ b_v,
        const float* __restrict__ w_pd, const float* __restrict__ b_pd,
        float* __restrict__ out, int n_nodes) {
    __shared__ float sh[32][128];
    __shared__ float sv[128], sd[128];
    const int t = threadIdx.x;
    const int d4 = t & 31, pg = t >> 5;
    float4 acc = make_float4(0.f, 0.f, 0.f, 0.f);
    for (int i = pg; i < nparts; i += 32) {
        float4 v = *(const float4*)(part + (size_t)i * 128 + d4 * 4);
        acc.x += v.x; acc.y += v.y; acc.z += v.z; acc.w += v.w;
    }
    *(float4*)&sh[pg][d4 * 4] = acc;
    __syncthreads();
    for (int off = 16; off > 0; off >>= 1) {
        if (pg < off) {
            float4 a = *(float4*)&sh[pg][d4 * 4];
            float4 b = *(float4*)&sh[pg + off][d4 * 4];
            a.x += b.x; a.y += b.y; a.z += b.z; a.w += b.w;
            *(float4*)&sh[pg][d4 * 4] = a;
        }
        __syncthreads();
    }
    if (t < 128) {
        float mm = sh[0][t] / (float)n_nodes;
        sv[t] = mm * w_v[t];
        sd[t] = mm * w_pd[t];
    }
    __syncthreads();
    for (int off = 64; off > 0; off >>= 1) {
        if (t < off) { sv[t] += sv[t + off]; sd[t] += sd[t + off]; }
        __syncthreads();
    }
    if (t == 0) {
        out[n_nodes] = sd[0] + b_pd[0];
        out[n_nodes + 1] = sv[0] + b_v[0];
    }
}

// ---------------------------------------------------------------- launcher
static inline size_t align_up(size_t v, size_t a) { return (v + a - 1) & ~(a - 1); }

extern "C" void kernel_launch(void* const* d_in, const int* in_sizes, int n_in,
                              void* d_out, int out_size, void* d_ws, size_t ws_size,
                              hipStream_t stream) {
    const float* x    = (const float*)d_in[0];
    const int*   src  = (const int*)d_in[1];
    const int*   dst  = (const int*)d_in[2];
    const float* W0   = (const float*)d_in[3];
    const float* b0   = (const float*)d_in[4];
    const float* W1   = (const float*)d_in[5];
    const float* b1   = (const float*)d_in[6];
    const float* W2   = (const float*)d_in[7];
    const float* b2   = (const float*)d_in[8];
    const float* w_pg = (const float*)d_in[9];
    const float* b_pg = (const float*)d_in[10];
    const float* w_pd = (const float*)d_in[11];
    const float* b_pd = (const float*)d_in[12];
    const float* w_v  = (const float*)d_in[13];
    const float* b_v  = (const float*)d_in[14];
    float* out = (float*)d_out;

    const int NN = in_sizes[0] / HID;          // 50000
    const int NE = in_sizes[1];                // 1600000
    const int NB = (NN + 63) >> BSH;           // coarse buckets
    const int SZ = NB * NBLK;                  // histogram table (~200K ints)
    const int EPB = (((NE + NBLK - 1) / NBLK) + 3) & ~3;  // x4 aligned
    const int NG = (SZ + SCAN_CHUNK - 1) / SCAN_CHUNK;
    const int GBLK = (NN + 63) / 64;           // gemm blocks (=part count)
    const int NDEG = NB * 64;                  // deg array (node-padded)

    // workspace carve-up
    char* w = (char*)d_ws;
    int* tbl      = (int*)w;            w += align_up((size_t)SZ * 4, 256);
    int* bsum     = (int*)w;            w += align_up((size_t)256 * 4, 256);
    int* deg      = (int*)w;            w += align_up((size_t)NDEG * 4, 256);
    int* row_ptr  = (int*)w;            w += align_up((size_t)(NN + 1) * 4, 256);
    int* eidx     = (int*)w;            w += align_up((size_t)NE * 4, 256);
    unsigned short* xb   = (unsigned short*)w; w += align_up((size_t)NN * HID * 2, 256);
    unsigned short* aggb = (unsigned short*)w; w += align_up((size_t)NN * HID * 2, 256);
    unsigned short* hb   = (unsigned short*)w; w += align_up((size_t)NN * HID * 2, 256);
    unsigned short* pw   = (unsigned short*)w; w += align_up((size_t)3 * 16384 * 2, 256);
    float* part   = (float*)w;          w += align_up((size_t)GBLK * 128 * 4, 256);
    int* pairs    = (int*)aggb;  // alias: pairs (6.4MB) dead before aggb written
    (void)ws_size; (void)n_in; (void)out_size;

    // ---- converts (also zeros deg)
    f32_to_bf16_kernel<<<2048, 256, 0, stream>>>((const float4*)x, (ushort4*)xb, NN * 32);
    pack_w3_kernel<<<64, 256, 0, stream>>>(W0, W1, W2, pw, (int4*)deg, NDEG / 4);

    // ---- build CSR by dst (reused for all 3 layers)
    bhist_kernel<<<NBLK, 256, 0, stream>>>(dst, tbl, deg, NE, NB, EPB);
    scan_p1_kernel<<<NG, 256, 0, stream>>>(tbl, bsum, SZ);
    scan_p2_kernel<<<1, 256, 0, stream>>>(bsum, NG);
    scan_p3_kernel<<<NG, 256, 0, stream>>>(tbl, bsum, SZ);
    bucket_scatter_kernel<<<NBLK, 256, 0, stream>>>(src, dst, tbl, pairs, NE, NB, EPB);
    fine_scatter_kernel<<<NB, 256, 0, stream>>>(pairs, tbl, deg, row_ptr, eidx, NE, NB, NN);

    const int agg_blocks = (NN * 32 + 255) / 256;

    aggregate_bf_kernel<<<agg_blocks, 256, 0, stream>>>((const uint4*)xb, row_ptr, eidx,
                                                        (uint4*)aggb, NN);
    gemm_mfma_kernel<<<GBLK, 256, 0, stream>>>((const short*)aggb, (const short*)pw,
                                               b0, hb, NN, nullptr, nullptr, nullptr, nullptr);
    aggregate_bf_kernel<<<agg_blocks, 256, 0, stream>>>((const uint4*)hb, row_ptr, eidx,
                                                        (uint4*)aggb, NN);
    gemm_mfma_kernel<<<GBLK, 256, 0, stream>>>((const short*)aggb, (const short*)(pw + 16384),
                                               b1, hb, NN, nullptr, nullptr, nullptr, nullptr);
    aggregate_bf_kernel<<<agg_blocks, 256, 0, stream>>>((const uint4*)hb, row_ptr, eidx,
                                                        (uint4*)aggb, NN);
    gemm_mfma_kernel<<<GBLK, 256, 0, stream>>>((const short*)aggb, (const short*)(pw + 32768),
                                               b2, hb, NN, part, out, w_pg, b_pg);

    // ---- mean head
    head_final_kernel<<<1, 1024, 0, stream>>>(part, GBLK, w_v, b_v, w_pd, b_pd, out, NN);
}

// Round 11
// 256.250 us; speedup vs baseline: 1.2559x; 1.2559x over previous
//
#include <hip/hip_runtime.h>
#include <hip/hip_bf16.h>

// GCN actor-critic, bf16 pipeline:
//   CSR build (counting sort) -> 3x [gather-sum -> MFMA GEMM+ReLU]
//   layer-3 GEMM epilogue emits pi_graph + per-block column partials.
// NOTE (r10 post-mortem): global per-node deg atomics in bhist = 56MB of
// random partial-line writes (+56us). Two-pass fine_scatter is cheaper.

#define HID 128
#define NBLK 256       // edge-partition blocks
#define BSH 6          // 64 nodes per coarse bucket
#define SCAN_CHUNK 1024

typedef __attribute__((ext_vector_type(8))) short short8;
typedef __attribute__((ext_vector_type(4))) float f32x4;
typedef __attribute__((ext_vector_type(2))) float f32x2;
typedef __attribute__((ext_vector_type(2))) unsigned int u32x2;

__device__ __forceinline__ unsigned int f2bf(float f) {
    unsigned int u = __float_as_uint(f);
    return (u + 0x7fffu + ((u >> 16) & 1u)) >> 16;   // RNE
}
__device__ __forceinline__ f32x2 bfpair(unsigned int u) {
    u32x2 t = {u << 16, u & 0xffff0000u};
    return __builtin_bit_cast(f32x2, t);
}

// ---------------------------------------------------------------- converts
__global__ __launch_bounds__(256) void f32_to_bf16_kernel(
        const float4* __restrict__ in, ushort4* __restrict__ out, int n4) {
    for (int i = blockIdx.x * blockDim.x + threadIdx.x; i < n4; i += gridDim.x * blockDim.x) {
        float4 v = in[i];
        ushort4 o;
        o.x = (unsigned short)f2bf(v.x); o.y = (unsigned short)f2bf(v.y);
        o.z = (unsigned short)f2bf(v.z); o.w = (unsigned short)f2bf(v.w);
        out[i] = o;
    }
}

// pack all 3 W[128][128] into B-fragment order:
// pw[L*16384 + ((c*4+kk)*64+lane)*8+i] = bf16(W_L[kk*32+(lane>>4)*8+i][c*16+(lane&15)])
__global__ __launch_bounds__(256) void pack_w3_kernel(
        const float* __restrict__ W0, const float* __restrict__ W1,
        const float* __restrict__ W2, unsigned short* __restrict__ pw) {
    for (int j = blockIdx.x * blockDim.x + threadIdx.x; j < 3 * 16384;
         j += gridDim.x * blockDim.x) {
        int jj = j & 16383, which = j >> 14;
        const float* W = (which == 0) ? W0 : (which == 1) ? W1 : W2;
        int i = jj & 7, lane = (jj >> 3) & 63, kk = (jj >> 9) & 3, c = (jj >> 11) & 7;
        int k = kk * 32 + (lane >> 4) * 8 + i;
        int col = c * 16 + (lane & 15);
        pw[j] = (unsigned short)f2bf(W[k * 128 + col]);
    }
}

// ---- 1. coarse histogram (int4 loads): tbl[b*NBLK+k] = edges of block k in b
__global__ __launch_bounds__(256) void bhist_kernel(const int* __restrict__ dst,
        int* __restrict__ tbl, int ne, int nb, int epb) {
    __shared__ int lcnt[1024];
    const int k = blockIdx.x, t = threadIdx.x;
    for (int b = t; b < nb; b += 256) lcnt[b] = 0;
    __syncthreads();
    const int beg = k * epb, end = min(ne, beg + epb);
    int j = beg + t * 4;
    for (; j + 3 < end; j += 1024) {
        int4 d = *(const int4*)(dst + j);
        atomicAdd(&lcnt[d.x >> BSH], 1);
        atomicAdd(&lcnt[d.y >> BSH], 1);
        atomicAdd(&lcnt[d.z >> BSH], 1);
        atomicAdd(&lcnt[d.w >> BSH], 1);
    }
    for (; j < end; ++j)
        atomicAdd(&lcnt[dst[j] >> BSH], 1);
    __syncthreads();
    for (int b = t; b < nb; b += 256) tbl[b * NBLK + k] = lcnt[b];
}

// ---- 2. hierarchical exclusive scan of tbl[0..sz)
__global__ __launch_bounds__(256) void scan_p1_kernel(const int* __restrict__ tbl,
        int* __restrict__ bsum, int sz) {
    __shared__ int sh[256];
    const int g = blockIdx.x, t = threadIdx.x;
    const int base = g * SCAN_CHUNK + t * 4;
    int s = 0;
    if (base + 3 < sz) {
        int4 v = *(const int4*)(tbl + base);
        s = v.x + v.y + v.z + v.w;
    } else {
        for (int i = 0; i < 4; ++i) if (base + i < sz) s += tbl[base + i];
    }
    sh[t] = s;
    __syncthreads();
    for (int off = 128; off > 0; off >>= 1) {
        if (t < off) sh[t] += sh[t + off];
        __syncthreads();
    }
    if (t == 0) bsum[g] = sh[0];
}

__global__ __launch_bounds__(256) void scan_p2_kernel(int* __restrict__ bsum, int ng) {
    __shared__ int sh[256];
    const int t = threadIdx.x;
    int v = (t < ng) ? bsum[t] : 0;
    sh[t] = v;
    __syncthreads();
    for (int off = 1; off < 256; off <<= 1) {
        int a = sh[t];
        int b = (t >= off) ? sh[t - off] : 0;
        __syncthreads();
        sh[t] = a + b;
        __syncthreads();
    }
    if (t < ng) bsum[t] = sh[t] - v;   // exclusive
}

__global__ __launch_bounds__(256) void scan_p3_kernel(int* __restrict__ tbl,
        const int* __restrict__ bsum, int sz) {
    __shared__ int sh[256];
    const int g = blockIdx.x, t = threadIdx.x;
    const int base = g * SCAN_CHUNK + t * 4;
    int4 v = make_int4(0, 0, 0, 0);
    if (base + 3 < sz) {
        v = *(const int4*)(tbl + base);
    } else {
        if (base + 0 < sz) v.x = tbl[base + 0];
        if (base + 1 < sz) v.y = tbl[base + 1];
        if (base + 2 < sz) v.z = tbl[base + 2];
    }
    int s = v.x + v.y + v.z + v.w;
    sh[t] = s;
    __syncthreads();
    for (int off = 1; off < 256; off <<= 1) {
        int a = sh[t];
        int b = (t >= off) ? sh[t - off] : 0;
        __syncthreads();
        sh[t] = a + b;
        __syncthreads();
    }
    int pre = bsum[g] + sh[t] - s;
    int o0 = pre, o1 = pre + v.x, o2 = o1 + v.y, o3 = o2 + v.z;
    if (base + 3 < sz) {
        *(int4*)(tbl + base) = make_int4(o0, o1, o2, o3);
    } else {
        if (base + 0 < sz) tbl[base + 0] = o0;
        if (base + 1 < sz) tbl[base + 1] = o1;
        if (base + 2 < sz) tbl[base + 2] = o2;
    }
}

// ---- 3. scatter edges into block-private per-bucket subranges (int4 loads)
__global__ __launch_bounds__(256) void bucket_scatter_kernel(
        const int* __restrict__ src, const int* __restrict__ dst,
        const int* __restrict__ tbl, int* __restrict__ pairs,
        int ne, int nb, int epb) {
    __shared__ int cur[1024];
    const int k = blockIdx.x, t = threadIdx.x;
    for (int b = t; b < nb; b += 256) cur[b] = tbl[b * NBLK + k];
    __syncthreads();
    const int beg = k * epb, end = min(ne, beg + epb);
    int j = beg + t * 4;
    for (; j + 3 < end; j += 1024) {
        int4 d = *(const int4*)(dst + j);
        int4 s = *(const int4*)(src + j);
        int p0 = atomicAdd(&cur[d.x >> BSH], 1); pairs[p0] = (s.x << BSH) | (d.x & 63);
        int p1 = atomicAdd(&cur[d.y >> BSH], 1); pairs[p1] = (s.y << BSH) | (d.y & 63);
        int p2 = atomicAdd(&cur[d.z >> BSH], 1); pairs[p2] = (s.z << BSH) | (d.z & 63);
        int p3 = atomicAdd(&cur[d.w >> BSH], 1); pairs[p3] = (s.w << BSH) | (d.w & 63);
    }
    for (; j < end; ++j) {
        int d = dst[j];
        int pos = atomicAdd(&cur[d >> BSH], 1);
        pairs[pos] = (src[j] << BSH) | (d & 63);
    }
}

// ---- 4. per-bucket fine scatter (two-pass, LDS count); writes row_ptr
__global__ __launch_bounds__(256) void fine_scatter_kernel(
        const int* __restrict__ pairs, const int* __restrict__ tbl,
        int* __restrict__ row_ptr, int* __restrict__ eidx,
        int ne, int nb, int n) {
    __shared__ int cnt[64], cur[64];
    const int b = blockIdx.x, t = threadIdx.x;
    const int node0 = b << BSH;
    if (t < 64) cnt[t] = 0;
    __syncthreads();
    const int beg = tbl[b * NBLK];
    const int end = (b == nb - 1) ? ne : tbl[(b + 1) * NBLK];
    for (int j = beg + t; j < end; j += 256) atomicAdd(&cnt[pairs[j] & 63], 1);
    __syncthreads();
    if (t == 0) {
        int run = beg;
        #pragma unroll
        for (int i = 0; i < 64; ++i) { cur[i] = run; run += cnt[i]; }
    }
    __syncthreads();
    if (t < 64 && node0 + t < n) row_ptr[node0 + t] = cur[t];
    if (b == nb - 1 && t == 0) row_ptr[n] = ne;
    __syncthreads();
    for (int j = beg + t; j < end; j += 256) {
        int v = pairs[j];
        int pos = atomicAdd(&cur[v & 63], 1);
        eidx[pos] = v >> BSH;
    }
}

// ------------------------------------------------------------- aggregation
// 32-lane group per node; half = lane>>4 picks even/odd edge, l16 = lane&15
// picks 16B (8 bf16 dims). f32x2 accumulators -> v_pk_add_f32.
#define ACC8(V)  { a01 += bfpair((V).x); a23 += bfpair((V).y);            \
                   a45 += bfpair((V).z); a67 += bfpair((V).w); }

__global__ __launch_bounds__(256) void aggregate_bf_kernel(
        const uint4* __restrict__ xb, const int* __restrict__ row_ptr,
        const int* __restrict__ eidx, uint4* __restrict__ aggb, int n) {
    int g = (int)((blockIdx.x * blockDim.x + threadIdx.x) >> 5);
    int lane = threadIdx.x & 31;
    if (g >= n) return;
    const int half = lane >> 4, l16 = lane & 15;
    const int beg = row_ptr[g], end = row_ptr[g + 1];
    f32x2 a01 = {0.f, 0.f}, a23 = {0.f, 0.f}, a45 = {0.f, 0.f}, a67 = {0.f, 0.f};
    int e = beg;
    for (; e + 16 <= end; e += 16) {
        uint4 v0 = xb[(size_t)eidx[e + 0 + half] * 16 + l16];
        uint4 v1 = xb[(size_t)eidx[e + 2 + half] * 16 + l16];
        uint4 v2 = xb[(size_t)eidx[e + 4 + half] * 16 + l16];
        uint4 v3 = xb[(size_t)eidx[e + 6 + half] * 16 + l16];
        uint4 v4 = xb[(size_t)eidx[e + 8 + half] * 16 + l16];
        uint4 v5 = xb[(size_t)eidx[e + 10 + half] * 16 + l16];
        uint4 v6 = xb[(size_t)eidx[e + 12 + half] * 16 + l16];
        uint4 v7 = xb[(size_t)eidx[e + 14 + half] * 16 + l16];
        ACC8(v0); ACC8(v1); ACC8(v2); ACC8(v3);
        ACC8(v4); ACC8(v5); ACC8(v6); ACC8(v7);
    }
    for (; e + 4 <= end; e += 4) {
        uint4 v0 = xb[(size_t)eidx[e + 0 + half] * 16 + l16];
        uint4 v1 = xb[(size_t)eidx[e + 2 + half] * 16 + l16];
        ACC8(v0); ACC8(v1);
    }
    for (; e < end; e += 2) {
        int idx = e + half;
        uint4 v = make_uint4(0, 0, 0, 0);
        if (idx < end) v = xb[(size_t)eidx[idx] * 16 + l16];
        ACC8(v);
    }
    float acc[8] = {a01.x, a01.y, a23.x, a23.y, a45.x, a45.y, a67.x, a67.y};
    #pragma unroll
    for (int j = 0; j < 8; ++j) acc[j] += __shfl_xor(acc[j], 16);
    if (half == 0) {
        uint4 o;
        o.x = f2bf(acc[0]) | (f2bf(acc[1]) << 16);
        o.y = f2bf(acc[2]) | (f2bf(acc[3]) << 16);
        o.z = f2bf(acc[4]) | (f2bf(acc[5]) << 16);
        o.w = f2bf(acc[6]) | (f2bf(acc[7]) << 16);
        aggb[(size_t)g * 16 + l16] = o;
    }
}

// ---------------------------------------------------------- GEMM bf16 MFMA
__global__ __launch_bounds__(256) void gemm_mfma_kernel(
        const short* __restrict__ A, const short* __restrict__ packw,
        const float* __restrict__ bias, unsigned short* __restrict__ out, int M,
        float* __restrict__ part, float* __restrict__ pig_out,
        const float* __restrict__ w_pg, const float* __restrict__ b_pg) {
    __shared__ float colp[4][128];
    const int w = threadIdx.x >> 6, l = threadIdx.x & 63;
    const int m = l & 15, hi = l >> 4;
    const int row0 = blockIdx.x * 64 + w * 16;
    const int arow = row0 + m;
    const bool valid = arow < M;

    short8 afrag[4];
    #pragma unroll
    for (int kk = 0; kk < 4; ++kk) {
        if (valid)
            afrag[kk] = *(const short8*)(A + (size_t)arow * 128 + kk * 32 + hi * 8);
        else
            afrag[kk] = short8{0, 0, 0, 0, 0, 0, 0, 0};
    }

    f32x4 acc[8] = {};
    #pragma unroll
    for (int kk = 0; kk < 4; ++kk) {
        #pragma unroll
        for (int c = 0; c < 8; ++c) {
            short8 bfrag = *(const short8*)(packw + ((size_t)(c * 4 + kk) * 64 + l) * 8);
            acc[c] = __builtin_amdgcn_mfma_f32_16x16x32_bf16(afrag[kk], bfrag, acc[c], 0, 0, 0);
        }
    }

    float hvv[8][4];
    #pragma unroll
    for (int c = 0; c < 8; ++c) {
        float bcol = bias[c * 16 + m];
        #pragma unroll
        for (int r = 0; r < 4; ++r) {
            int row = row0 + hi * 4 + r;
            float hv = (row < M) ? fmaxf(acc[c][r] + bcol, 0.f) : 0.f;
            hvv[c][r] = hv;
            if (row < M)
                out[(size_t)row * 128 + c * 16 + m] = (unsigned short)f2bf(hv);
        }
    }

    if (w_pg) {
        #pragma unroll
        for (int r = 0; r < 4; ++r) {
            float p = 0.f;
            #pragma unroll
            for (int c = 0; c < 8; ++c) p += hvv[c][r] * w_pg[c * 16 + m];
            #pragma unroll
            for (int off = 1; off < 16; off <<= 1) p += __shfl_xor(p, off);
            int row = row0 + hi * 4 + r;
            if (m == 0 && row < M) pig_out[row] = p + b_pg[0];
        }
        #pragma unroll
        for (int c = 0; c < 8; ++c) {
            float v = hvv[c][0] + hvv[c][1] + hvv[c][2] + hvv[c][3];
            v += __shfl_xor(v, 16);
            v += __shfl_xor(v, 32);
            if (hi == 0) colp[w][c * 16 + m] = v;
        }
        __syncthreads();
        const int t = threadIdx.x;
        if (t < 128)
            part[(size_t)blockIdx.x * 128 + t] =
                colp[0][t] + colp[1][t] + colp[2][t] + colp[3][t];
    }
}

// ---------------------------------------------------------------- head
__global__ __launch_bounds__(1024) void head_final_kernel(
        const float* __restrict__ part, int nparts,
        const float* __restrict__ w_v, const float* __restrict__ b_v,
        const float* __restrict__ w_pd, const float* __restrict__ b_pd,
        float* __restrict__ out, int n_nodes) {
    __shared__ float sh[32][128];
    __shared__ float sv[128], sd[128];
    const int t = threadIdx.x;
    const int d4 = t & 31, pg = t >> 5;
    float4 acc = make_float4(0.f, 0.f, 0.f, 0.f);
    for (int i = pg; i < nparts; i += 32) {
        float4 v = *(const float4*)(part + (size_t)i * 128 + d4 * 4);
        acc.x += v.x; acc.y += v.y; acc.z += v.z; acc.w += v.w;
    }
    *(float4*)&sh[pg][d4 * 4] = acc;
    __syncthreads();
    for (int off = 16; off > 0; off >>= 1) {
        if (pg < off) {
            float4 a = *(float4*)&sh[pg][d4 * 4];
            float4 b = *(float4*)&sh[pg + off][d4 * 4];
            a.x += b.x; a.y += b.y; a.z += b.z; a.w += b.w;
            *(float4*)&sh[pg][d4 * 4] = a;
        }
        __syncthreads();
    }
    if (t < 128) {
        float mm = sh[0][t] / (float)n_nodes;
        sv[t] = mm * w_v[t];
        sd[t] = mm * w_pd[t];
    }
    __syncthreads();
    for (int off = 64; off > 0; off >>= 1) {
        if (t < off) { sv[t] += sv[t + off]; sd[t] += sd[t + off]; }
        __syncthreads();
    }
    if (t == 0) {
        out[n_nodes] = sd[0] + b_pd[0];
        out[n_nodes + 1] = sv[0] + b_v[0];
    }
}

// ---------------------------------------------------------------- launcher
static inline size_t align_up(size_t v, size_t a) { return (v + a - 1) & ~(a - 1); }

extern "C" void kernel_launch(void* const* d_in, const int* in_sizes, int n_in,
                              void* d_out, int out_size, void* d_ws, size_t ws_size,
                              hipStream_t stream) {
    const float* x    = (const float*)d_in[0];
    const int*   src  = (const int*)d_in[1];
    const int*   dst  = (const int*)d_in[2];
    const float* W0   = (const float*)d_in[3];
    const float* b0   = (const float*)d_in[4];
    const float* W1   = (const float*)d_in[5];
    const float* b1   = (const float*)d_in[6];
    const float* W2   = (const float*)d_in[7];
    const float* b2   = (const float*)d_in[8];
    const float* w_pg = (const float*)d_in[9];
    const float* b_pg = (const float*)d_in[10];
    const float* w_pd = (const float*)d_in[11];
    const float* b_pd = (const float*)d_in[12];
    const float* w_v  = (const float*)d_in[13];
    const float* b_v  = (const float*)d_in[14];
    float* out = (float*)d_out;

    const int NN = in_sizes[0] / HID;          // 50000
    const int NE = in_sizes[1];                // 1600000
    const int NB = (NN + 63) >> BSH;           // coarse buckets
    const int SZ = NB * NBLK;                  // histogram table (~200K ints)
    const int EPB = (((NE + NBLK - 1) / NBLK) + 3) & ~3;  // x4 aligned
    const int NG = (SZ + SCAN_CHUNK - 1) / SCAN_CHUNK;
    const int GBLK = (NN + 63) / 64;           // gemm blocks (=part count)

    // workspace carve-up
    char* w = (char*)d_ws;
    int* tbl      = (int*)w;            w += align_up((size_t)SZ * 4, 256);
    int* bsum     = (int*)w;            w += align_up((size_t)256 * 4, 256);
    int* row_ptr  = (int*)w;            w += align_up((size_t)(NN + 1) * 4, 256);
    int* eidx     = (int*)w;            w += align_up((size_t)NE * 4, 256);
    unsigned short* xb   = (unsigned short*)w; w += align_up((size_t)NN * HID * 2, 256);
    unsigned short* aggb = (unsigned short*)w; w += align_up((size_t)NN * HID * 2, 256);
    unsigned short* hb   = (unsigned short*)w; w += align_up((size_t)NN * HID * 2, 256);
    unsigned short* pw   = (unsigned short*)w; w += align_up((size_t)3 * 16384 * 2, 256);
    float* part   = (float*)w;          w += align_up((size_t)GBLK * 128 * 4, 256);
    int* pairs    = (int*)aggb;  // alias: pairs (6.4MB) dead before aggb written
    (void)ws_size; (void)n_in; (void)out_size;

    // ---- converts (independent of CSR)
    f32_to_bf16_kernel<<<2048, 256, 0, stream>>>((const float4*)x, (ushort4*)xb, NN * 32);
    pack_w3_kernel<<<48, 256, 0, stream>>>(W0, W1, W2, pw);

    // ---- build CSR by dst (reused for all 3 layers)
    bhist_kernel<<<NBLK, 256, 0, stream>>>(dst, tbl, NE, NB, EPB);
    scan_p1_kernel<<<NG, 256, 0, stream>>>(tbl, bsum, SZ);
    scan_p2_kernel<<<1, 256, 0, stream>>>(bsum, NG);
    scan_p3_kernel<<<NG, 256, 0, stream>>>(tbl, bsum, SZ);
    bucket_scatter_kernel<<<NBLK, 256, 0, stream>>>(src, dst, tbl, pairs, NE, NB, EPB);
    fine_scatter_kernel<<<NB, 256, 0, stream>>>(pairs, tbl, row_ptr, eidx, NE, NB, NN);

    const int agg_blocks = (NN * 32 + 255) / 256;

    aggregate_bf_kernel<<<agg_blocks, 256, 0, stream>>>((const uint4*)xb, row_ptr, eidx,
                                                        (uint4*)aggb, NN);
    gemm_mfma_kernel<<<GBLK, 256, 0, stream>>>((const short*)aggb, (const short*)pw,
                                               b0, hb, NN, nullptr, nullptr, nullptr, nullptr);
    aggregate_bf_kernel<<<agg_blocks, 256, 0, stream>>>((const uint4*)hb, row_ptr, eidx,
                                                        (uint4*)aggb, NN);
    gemm_mfma_kernel<<<GBLK, 256, 0, stream>>>((const short*)aggb, (const short*)(pw + 16384),
                                               b1, hb, NN, nullptr, nullptr, nullptr, nullptr);
    aggregate_bf_kernel<<<agg_blocks, 256, 0, stream>>>((const uint4*)hb, row_ptr, eidx,
                                                        (uint4*)aggb, NN);
    gemm_mfma_kernel<<<GBLK, 256, 0, stream>>>((const short*)aggb, (const short*)(pw + 32768),
                                               b2, hb, NN, part, out, w_pg, b_pg);

    // ---- mean head
    head_final_kernel<<<1, 1024, 0, stream>>>(part, GBLK, w_v, b_v, w_pd, b_pd, out, NN);
}